// Round 1
// baseline (3855.327 us; speedup 1.0000x reference)
//
#include <hip/hip_runtime.h>

// Problem constants (B=128, S=196, K=512, T=15, V=32000, E=H=512)
typedef _Float16 half_t;
typedef float    floatx4 __attribute__((ext_vector_type(4)));
typedef _Float16 halfx8  __attribute__((ext_vector_type(8)));
typedef _Float16 halfx4  __attribute__((ext_vector_type(4)));
typedef _Float16 halfx2  __attribute__((ext_vector_type(2)));

__device__ __forceinline__ float tanh_f(float x) {
  float e = __expf(2.0f * x);
  return 1.0f - 2.0f / (e + 1.0f);
}
__device__ __forceinline__ float sigmoid_f(float x) {
  return 1.0f / (1.0f + __expf(-x));
}

// ---------------- f32 -> f16 convert ----------------
__global__ __launch_bounds__(256) void k_cvt_f16(const float* __restrict__ src,
                                                 half_t* __restrict__ dst, int n) {
  int i = (blockIdx.x * 256 + threadIdx.x) * 4;
  if (i < n) {
    float4 v = *(const float4*)(src + i);
    halfx4 o;
    o[0] = (half_t)v.x; o[1] = (half_t)v.y; o[2] = (half_t)v.z; o[3] = (half_t)v.w;
    *(halfx4*)(dst + i) = o;
  }
}

// ---------------- embedding gather -> f16 (rows b*15+t) ----------------
__global__ __launch_bounds__(256) void k_gather(const float* __restrict__ emb,
                                                const int* __restrict__ cap,
                                                half_t* __restrict__ dst) {
  int row = blockIdx.x;              // b*15 + t
  int b = row / 15, t = row - b * 15;
  int c = cap[b * 16 + t];
  const float* s = emb + (size_t)c * 512;
  int e = threadIdx.x * 2;
  float2 v = *(const float2*)(s + e);
  halfx2 o; o[0] = (half_t)v.x; o[1] = (half_t)v.y;
  *(halfx2*)(dst + (size_t)row * 512 + e) = o;
}

__global__ __launch_bounds__(256) void k_zero(float4* p) {
  p[blockIdx.x * 256 + threadIdx.x] = make_float4(0.f, 0.f, 0.f, 0.f);
}

// ---------------- fp16 MFMA GEMM: C[m][n] = sum_k A[m][k]*B[n][k] (+bias[n]) ----------------
// A, B row-major with K inner. Block = 256 thr = 4 waves, tile 128(m) x 128(n).
// No LDS: fragments loaded directly from global (M small; B rows read once per block).
// Layouts per cdna_hip_programming.md §3 (HW-verified m89/m91):
//   A/B operand: idx = lane&15, k = (lane>>4)*8 + j ;  C/D: row m=(lane>>4)*4+r, col n=lane&15
template <bool A_F32, bool OUT_F16>
__global__ __launch_bounds__(256) void k_gemm_bt(const void* __restrict__ Ap,
                                                 const half_t* __restrict__ Bp,
                                                 const float* __restrict__ bias,
                                                 void* __restrict__ Cp,
                                                 int Kd, int ldc) {
  const int l = threadIdx.x & 63;
  const int w = threadIdx.x >> 6;
  const int m0 = blockIdx.x * 128 + (w & 1) * 64;
  const int n0 = blockIdx.y * 128 + (w >> 1) * 64;
  const int fr = l & 15;
  const int kq = (l >> 4) * 8;
  floatx4 acc[4][4];
#pragma unroll
  for (int i = 0; i < 4; ++i)
#pragma unroll
    for (int j = 0; j < 4; ++j) { floatx4 z = {0.f, 0.f, 0.f, 0.f}; acc[i][j] = z; }

  for (int k0 = 0; k0 < Kd; k0 += 32) {
    halfx8 af[4], bf[4];
#pragma unroll
    for (int i = 0; i < 4; ++i) {
      size_t arow = (size_t)(m0 + i * 16 + fr) * Kd + k0 + kq;
      if (A_F32) {
        const float* ap = (const float*)Ap + arow;
        float4 v0 = *(const float4*)ap;
        float4 v1 = *(const float4*)(ap + 4);
        halfx8 a;
        a[0] = (half_t)v0.x; a[1] = (half_t)v0.y; a[2] = (half_t)v0.z; a[3] = (half_t)v0.w;
        a[4] = (half_t)v1.x; a[5] = (half_t)v1.y; a[6] = (half_t)v1.z; a[7] = (half_t)v1.w;
        af[i] = a;
      } else {
        af[i] = *(const halfx8*)((const half_t*)Ap + arow);
      }
      bf[i] = *(const halfx8*)(Bp + (size_t)(n0 + i * 16 + fr) * Kd + k0 + kq);
    }
#pragma unroll
    for (int i = 0; i < 4; ++i)
#pragma unroll
      for (int j = 0; j < 4; ++j)
        acc[i][j] = __builtin_amdgcn_mfma_f32_16x16x32_f16(af[i], bf[j], acc[i][j], 0, 0, 0);
  }

#pragma unroll
  for (int j = 0; j < 4; ++j) {
    int n = n0 + j * 16 + (l & 15);
    float bv = bias ? bias[n] : 0.0f;
#pragma unroll
    for (int i = 0; i < 4; ++i) {
      int mb = m0 + i * 16 + (l >> 4) * 4;
#pragma unroll
      for (int r = 0; r < 4; ++r) {
        float v = acc[i][j][r] + bv;
        size_t ci = (size_t)(mb + r) * ldc + n;
        if (OUT_F16) ((half_t*)Cp)[ci] = (half_t)v;
        else         ((float*)Cp)[ci] = v;
      }
    }
  }
}

// ---------------- fused attention per batch row (f32) ----------------
// q = h@wq^T ; scores = tanh(q+kp)@att_v ; softmax ; ctx = w@features ; ctxo = ctx@fc0^T+b
__global__ __launch_bounds__(256) void k_attn(const float* __restrict__ h,
                                              const half_t* __restrict__ kp,
                                              const float* __restrict__ feat,
                                              const float* __restrict__ wq,
                                              const float* __restrict__ attv,
                                              const float* __restrict__ fc0w,
                                              const float* __restrict__ fc0b,
                                              float* __restrict__ ctxo) {
  const int b = blockIdx.x, t = threadIdx.x;
  __shared__ float hs[512], qs[512], sw[200], red[256], cs[512];
  if (t < 128) ((float4*)hs)[t] = ((const float4*)(h + (size_t)b * 512))[t];
  __syncthreads();
  {
    float a0 = 0.f, a1 = 0.f;
    const float4* w0 = (const float4*)(wq + (size_t)t * 512);
    const float4* w1 = (const float4*)(wq + (size_t)(t + 256) * 512);
#pragma unroll 4
    for (int k4 = 0; k4 < 128; ++k4) {
      float4 hv = ((const float4*)hs)[k4];
      float4 x0 = w0[k4], x1 = w1[k4];
      a0 += hv.x * x0.x + hv.y * x0.y + hv.z * x0.z + hv.w * x0.w;
      a1 += hv.x * x1.x + hv.y * x1.y + hv.z * x1.z + hv.w * x1.w;
    }
    qs[t] = a0; qs[t + 256] = a1;
  }
  __syncthreads();
  float sc = -1e30f;
  if (t < 196) {
    const half_t* kr = kp + (size_t)(b * 196 + t) * 512;
    float acc = 0.f;
    for (int k = 0; k < 512; k += 4) {
      halfx4 kv = *(const halfx4*)(kr + k);
      float4 qv = *(const float4*)(qs + k);
      float4 av = *(const float4*)(attv + k);
      acc += av.x * tanh_f(qv.x + (float)kv[0]);
      acc += av.y * tanh_f(qv.y + (float)kv[1]);
      acc += av.z * tanh_f(qv.z + (float)kv[2]);
      acc += av.w * tanh_f(qv.w + (float)kv[3]);
    }
    sc = acc;
  }
  red[t] = sc; __syncthreads();
  for (int o = 128; o > 0; o >>= 1) { if (t < o) red[t] = fmaxf(red[t], red[t + o]); __syncthreads(); }
  float mx = red[0]; __syncthreads();
  float e = (t < 196) ? __expf(sc - mx) : 0.f;
  red[t] = e; __syncthreads();
  for (int o = 128; o > 0; o >>= 1) { if (t < o) red[t] += red[t + o]; __syncthreads(); }
  float inv = 1.0f / red[0];
  if (t < 196) sw[t] = e * inv;
  __syncthreads();
  {
    float c0 = 0.f, c1 = 0.f;
    const float* fb = feat + (size_t)b * 196 * 512 + t;
#pragma unroll 4
    for (int s = 0; s < 196; ++s) {
      float wv = sw[s];
      c0 += wv * fb[(size_t)s * 512];
      c1 += wv * fb[(size_t)s * 512 + 256];
    }
    cs[t] = c0; cs[t + 256] = c1;
  }
  __syncthreads();
  {
    float a0 = fc0b[t], a1 = fc0b[t + 256];
    const float4* w0 = (const float4*)(fc0w + (size_t)t * 512);
    const float4* w1 = (const float4*)(fc0w + (size_t)(t + 256) * 512);
#pragma unroll 4
    for (int k4 = 0; k4 < 128; ++k4) {
      float4 cv = ((const float4*)cs)[k4];
      float4 x0 = w0[k4], x1 = w1[k4];
      a0 += cv.x * x0.x + cv.y * x0.y + cv.z * x0.z + cv.w * x0.w;
      a1 += cv.x * x1.x + cv.y * x1.y + cv.z * x1.z + cv.w * x1.w;
    }
    ctxo[(size_t)b * 512 + t] = a0;
    ctxo[(size_t)b * 512 + t + 256] = a1;
  }
}

// ---------------- GRU matmuls (f32, no bias): gi = rnn_in@wih^T, gh = h@whh^T ----------------
// blocks [0,192): gi, n-tile 8, K=1024 (k<512 from x_proj row b*15+t, else ctxo)
// blocks [192,288): gh, n-tile 16, K=512
__global__ __launch_bounds__(256) void k_gru(const float* __restrict__ xproj,
                                             const float* __restrict__ ctxo,
                                             const float* __restrict__ h,
                                             const float* __restrict__ wih,
                                             const float* __restrict__ whh,
                                             float* __restrict__ gi,
                                             float* __restrict__ gh, int t) {
  __shared__ float As[128][66];   // stride 66 words: conflict-free b64 reads for both paths
  const int tid = threadIdx.x;
  const int bi = blockIdx.x;
  if (bi < 192) {
    const int n0 = bi * 8;
    const int nl = tid & 7, mg = tid >> 3;
    float acc[4] = {0.f, 0.f, 0.f, 0.f};
    const float* brow = wih + (size_t)(n0 + nl) * 1024;
    for (int k0 = 0; k0 < 1024; k0 += 64) {
      __syncthreads();
      for (int i = tid; i < 2048; i += 256) {
        int m = i >> 4, j4 = (i & 15) * 4;
        int k = k0 + j4;
        float4 v;
        if (k < 512) v = *(const float4*)(xproj + (size_t)(m * 15 + t) * 512 + k);
        else         v = *(const float4*)(ctxo + (size_t)m * 512 + (k - 512));
        *(float2*)&As[m][j4]     = make_float2(v.x, v.y);
        *(float2*)&As[m][j4 + 2] = make_float2(v.z, v.w);
      }
      __syncthreads();
#pragma unroll 8
      for (int k = 0; k < 64; k += 2) {
        float2 bv = *(const float2*)(brow + k0 + k);
#pragma unroll
        for (int mm = 0; mm < 4; ++mm) {
          float2 av = *(const float2*)&As[mg * 4 + mm][k];
          acc[mm] += bv.x * av.x + bv.y * av.y;
        }
      }
    }
#pragma unroll
    for (int mm = 0; mm < 4; ++mm)
      gi[(size_t)(mg * 4 + mm) * 1536 + n0 + nl] = acc[mm];
  } else {
    const int n0 = (bi - 192) * 16;
    const int nl = tid & 15, mg = tid >> 4;
    float acc[8] = {0.f, 0.f, 0.f, 0.f, 0.f, 0.f, 0.f, 0.f};
    const float* brow = whh + (size_t)(n0 + nl) * 512;
    for (int k0 = 0; k0 < 512; k0 += 64) {
      __syncthreads();
      for (int i = tid; i < 2048; i += 256) {
        int m = i >> 4, j4 = (i & 15) * 4;
        float4 v = *(const float4*)(h + (size_t)m * 512 + k0 + j4);
        *(float2*)&As[m][j4]     = make_float2(v.x, v.y);
        *(float2*)&As[m][j4 + 2] = make_float2(v.z, v.w);
      }
      __syncthreads();
#pragma unroll 8
      for (int k = 0; k < 64; k += 2) {
        float2 bv = *(const float2*)(brow + k0 + k);
#pragma unroll
        for (int mm = 0; mm < 8; ++mm) {
          float2 av = *(const float2*)&As[mg * 8 + mm][k];
          acc[mm] += bv.x * av.x + bv.y * av.y;
        }
      }
    }
#pragma unroll
    for (int mm = 0; mm < 8; ++mm)
      gh[(size_t)(mg * 8 + mm) * 1536 + n0 + nl] = acc[mm];
  }
}

// ---------------- GRU gates (elementwise, h updated in place) ----------------
__global__ __launch_bounds__(256) void k_gates(const float* __restrict__ gi,
                                               const float* __restrict__ gh,
                                               const float* __restrict__ bih,
                                               const float* __restrict__ bhh,
                                               float* __restrict__ h,
                                               half_t* __restrict__ hh) {
  int b = blockIdx.x;
  size_t gb = (size_t)b * 1536;
  for (int idx = threadIdx.x; idx < 512; idx += 256) {
    float ir  = gi[gb + idx]        + bih[idx];
    float hr  = gh[gb + idx]        + bhh[idx];
    float iz  = gi[gb + 512 + idx]  + bih[512 + idx];
    float hz  = gh[gb + 512 + idx]  + bhh[512 + idx];
    float inn = gi[gb + 1024 + idx] + bih[1024 + idx];
    float hn  = gh[gb + 1024 + idx] + bhh[1024 + idx];
    float r = sigmoid_f(ir + hr);
    float z = sigmoid_f(iz + hz);
    float n = tanh_f(inn + r * hn);
    float hv = (1.0f - z) * n + z * h[(size_t)b * 512 + idx];
    h[(size_t)b * 512 + idx] = hv;
    hh[(size_t)b * 512 + idx] = (half_t)hv;
  }
}

extern "C" void kernel_launch(void* const* d_in, const int* in_sizes, int n_in,
                              void* d_out, int out_size, void* d_ws, size_t ws_size,
                              hipStream_t stream) {
  (void)in_sizes; (void)n_in; (void)out_size; (void)ws_size;
  const float* features = (const float*)d_in[0];
  const int*   captions = (const int*)d_in[1];
  const float* emb      = (const float*)d_in[2];
  const float* fc1_w    = (const float*)d_in[3];
  const float* fc1_b    = (const float*)d_in[4];
  const float* att_wq   = (const float*)d_in[5];
  const float* att_wk   = (const float*)d_in[6];
  const float* att_v    = (const float*)d_in[7];
  const float* fc0_w    = (const float*)d_in[8];
  const float* fc0_b    = (const float*)d_in[9];
  const float* gru_wih  = (const float*)d_in[10];
  const float* gru_whh  = (const float*)d_in[11];
  const float* gru_bih  = (const float*)d_in[12];
  const float* gru_bhh  = (const float*)d_in[13];
  const float* fc2_w    = (const float*)d_in[14];
  const float* fc2_b    = (const float*)d_in[15];
  float* out = (float*)d_out;

  // workspace layout (~64.5 MB)
  char* p = (char*)d_ws;
  half_t* kp     = (half_t*)p; p += (size_t)25088 * 512 * 2;   // keys_proj f16
  half_t* fc2w_h = (half_t*)p; p += (size_t)32000 * 512 * 2;
  half_t* fc1w_h = (half_t*)p; p += (size_t)512 * 512 * 2;
  half_t* wk_h   = (half_t*)p; p += (size_t)512 * 512 * 2;
  half_t* embg_h = (half_t*)p; p += (size_t)1920 * 512 * 2;
  half_t* h_h    = (half_t*)p; p += (size_t)128 * 512 * 2;
  float*  xproj  = (float*)p;  p += (size_t)1920 * 512 * 4;
  float*  hbuf   = (float*)p;  p += (size_t)128 * 512 * 4;
  float*  ctxo   = (float*)p;  p += (size_t)128 * 512 * 4;
  float*  gi     = (float*)p;  p += (size_t)128 * 1536 * 4;
  float*  gh     = (float*)p;  p += (size_t)128 * 1536 * 4;

  // precompute
  k_cvt_f16<<<dim3(16000), 256, 0, stream>>>(fc2_w, fc2w_h, 32000 * 512);
  k_cvt_f16<<<dim3(256),   256, 0, stream>>>(fc1_w, fc1w_h, 512 * 512);
  k_cvt_f16<<<dim3(256),   256, 0, stream>>>(att_wk, wk_h, 512 * 512);
  k_gather<<<dim3(1920), 256, 0, stream>>>(emb, captions, embg_h);
  k_zero<<<dim3(64), 256, 0, stream>>>((float4*)hbuf);
  // x_proj = embg @ fc1_w^T + fc1_b   (M=1920, N=512, K=512)
  k_gemm_bt<false, false><<<dim3(15, 4), 256, 0, stream>>>(embg_h, fc1w_h, fc1_b, xproj, 512, 512);
  // keys_proj = features @ att_wk^T   (M=25088, N=512, K=512), f32 A cvt in-kernel, f16 out
  k_gemm_bt<true, true><<<dim3(196, 4), 256, 0, stream>>>(features, wk_h, nullptr, kp, 512, 512);

  for (int t = 0; t < 15; ++t) {
    k_attn<<<dim3(128), 256, 0, stream>>>(hbuf, kp, features, att_wq, att_v, fc0_w, fc0_b, ctxo);
    k_gru<<<dim3(288), 256, 0, stream>>>(xproj, ctxo, hbuf, gru_wih, gru_whh, gi, gh, t);
    k_gates<<<dim3(128), 256, 0, stream>>>(gi, gh, gru_bih, gru_bhh, hbuf, h_h);
    // out[:, t, :] = h @ fc2_w^T + fc2_b   (M=128, N=32000, K=512)
    k_gemm_bt<false, false><<<dim3(1, 250), 256, 0, stream>>>(
        h_h, fc2w_h, fc2_b, out + (size_t)t * 32000, 512, 15 * 32000);
  }
}

// Round 2
// 1660.473 us; speedup vs baseline: 2.3218x; 2.3218x over previous
//
#include <hip/hip_runtime.h>

// B=128, S=196, K=512, T=15, V=32000, E=H=512
typedef _Float16 half_t;
typedef float    floatx4 __attribute__((ext_vector_type(4)));
typedef _Float16 halfx8  __attribute__((ext_vector_type(8)));
typedef _Float16 halfx2  __attribute__((ext_vector_type(2)));

__device__ __forceinline__ float tanh_f(float x) {
  float e = __expf(2.0f * x);
  return 1.0f - 2.0f / (e + 1.0f);
}
__device__ __forceinline__ float sigmoid_f(float x) {
  return 1.0f / (1.0f + __expf(-x));
}

// ---------------- f32 -> f16 convert ----------------
__global__ __launch_bounds__(256) void k_cvt_f16(const float* __restrict__ src,
                                                 half_t* __restrict__ dst, int n) {
  int i = (blockIdx.x * 256 + threadIdx.x) * 4;
  if (i < n) {
    float4 v = *(const float4*)(src + i);
    halfx8 o;  // only 4 used
    halfx2 a; a[0] = (half_t)v.x; a[1] = (half_t)v.y;
    halfx2 b; b[0] = (half_t)v.z; b[1] = (half_t)v.w;
    *(halfx2*)(dst + i) = a;
    *(halfx2*)(dst + i + 2) = b;
    (void)o;
  }
}

// split wih (1536x1024 f32) into wihx (cols 0:512) and wihc (cols 512:1024), f16
__global__ __launch_bounds__(256) void k_wihsplit(const float* __restrict__ wih,
                                                  half_t* __restrict__ wx,
                                                  half_t* __restrict__ wc) {
  int row = blockIdx.x, j = threadIdx.x * 2;
  float2 a = *(const float2*)(wih + (size_t)row * 1024 + j);
  float2 b = *(const float2*)(wih + (size_t)row * 1024 + 512 + j);
  halfx2 ax; ax[0] = (half_t)a.x; ax[1] = (half_t)a.y;
  halfx2 bx; bx[0] = (half_t)b.x; bx[1] = (half_t)b.y;
  *(halfx2*)(wx + (size_t)row * 512 + j) = ax;
  *(halfx2*)(wc + (size_t)row * 512 + j) = bx;
}

// ---------------- embedding gather -> f16 (rows b*15+t) ----------------
__global__ __launch_bounds__(256) void k_gather(const float* __restrict__ emb,
                                                const int* __restrict__ cap,
                                                half_t* __restrict__ dst) {
  int row = blockIdx.x;              // b*15 + t
  int b = row / 15, t = row - b * 15;
  int c = cap[b * 16 + t];
  const float* s = emb + (size_t)c * 512;
  int e = threadIdx.x * 2;
  float2 v = *(const float2*)(s + e);
  halfx2 o; o[0] = (half_t)v.x; o[1] = (half_t)v.y;
  *(halfx2*)(dst + (size_t)row * 512 + e) = o;
}

// biasc[0:512]=0, biasc[512:1024]=fc0_b
__global__ __launch_bounds__(256) void k_biasc(const float* __restrict__ fc0b,
                                               float* __restrict__ biasc) {
  int i = blockIdx.x * 256 + threadIdx.x;
  biasc[i] = (i < 512) ? 0.f : fc0b[i - 512];
}

__global__ __launch_bounds__(256) void k_zero(float4* p) {
  p[blockIdx.x * 256 + threadIdx.x] = make_float4(0.f, 0.f, 0.f, 0.f);
}

// ---------------- fp16 MFMA GEMM: C[m][n] = sum_k A[m][k]*B[n][k] (+bias[n]) ----------------
// tile 128m x 128n per block (4 waves, 64x64 each). Layouts per m89/m91.
template <bool A_F32, bool OUT_F16>
__global__ __launch_bounds__(256) void k_gemm_bt(const void* __restrict__ Ap,
                                                 const half_t* __restrict__ Bp,
                                                 const float* __restrict__ bias,
                                                 void* __restrict__ Cp,
                                                 int Kd, int ldc) {
  const int l = threadIdx.x & 63;
  const int w = threadIdx.x >> 6;
  const int m0 = blockIdx.x * 128 + (w & 1) * 64;
  const int n0 = blockIdx.y * 128 + (w >> 1) * 64;
  const int fr = l & 15;
  const int kq = (l >> 4) * 8;
  floatx4 acc[4][4];
#pragma unroll
  for (int i = 0; i < 4; ++i)
#pragma unroll
    for (int j = 0; j < 4; ++j) { floatx4 z = {0.f, 0.f, 0.f, 0.f}; acc[i][j] = z; }

  for (int k0 = 0; k0 < Kd; k0 += 32) {
    halfx8 af[4], bf[4];
#pragma unroll
    for (int i = 0; i < 4; ++i) {
      size_t arow = (size_t)(m0 + i * 16 + fr) * Kd + k0 + kq;
      if (A_F32) {
        const float* ap = (const float*)Ap + arow;
        float4 v0 = *(const float4*)ap;
        float4 v1 = *(const float4*)(ap + 4);
        halfx8 a;
        a[0] = (half_t)v0.x; a[1] = (half_t)v0.y; a[2] = (half_t)v0.z; a[3] = (half_t)v0.w;
        a[4] = (half_t)v1.x; a[5] = (half_t)v1.y; a[6] = (half_t)v1.z; a[7] = (half_t)v1.w;
        af[i] = a;
      } else {
        af[i] = *(const halfx8*)((const half_t*)Ap + arow);
      }
      bf[i] = *(const halfx8*)(Bp + (size_t)(n0 + i * 16 + fr) * Kd + k0 + kq);
    }
#pragma unroll
    for (int i = 0; i < 4; ++i)
#pragma unroll
      for (int j = 0; j < 4; ++j)
        acc[i][j] = __builtin_amdgcn_mfma_f32_16x16x32_f16(af[i], bf[j], acc[i][j], 0, 0, 0);
  }

#pragma unroll
  for (int j = 0; j < 4; ++j) {
    int n = n0 + j * 16 + (l & 15);
    float bv = bias ? bias[n] : 0.0f;
#pragma unroll
    for (int i = 0; i < 4; ++i) {
      int mb = m0 + i * 16 + (l >> 4) * 4;
#pragma unroll
      for (int r = 0; r < 4; ++r) {
        float v = acc[i][j][r] + bv;
        size_t ci = (size_t)(mb + r) * ldc + n;
        if (OUT_F16) ((half_t*)Cp)[ci] = (half_t)v;
        else         ((float*)Cp)[ci] = v;
      }
    }
  }
}

// ---------------- fc2 + [gh|q] fused GEMM: A = h_h (128x512 f16) ----------------
// blocks [0,250): C=out (+fc2_b), ldc=480000 ; blocks [250,266): C=ghq (128x2048 f32)
__global__ __launch_bounds__(256) void k_fc2gru(const half_t* __restrict__ hh,
                                                const half_t* __restrict__ fc2w,
                                                const float* __restrict__ fc2b,
                                                const half_t* __restrict__ bcat2,
                                                float* __restrict__ outp,
                                                float* __restrict__ ghq) {
  const int l = threadIdx.x & 63;
  const int w = threadIdx.x >> 6;
  const bool isfc2 = blockIdx.x < 250;
  const int nbase = isfc2 ? blockIdx.x * 128 : (blockIdx.x - 250) * 128;
  const int m0 = (w & 1) * 64;
  const int n0 = nbase + (w >> 1) * 64;
  const half_t* Bp = isfc2 ? fc2w : bcat2;
  const int fr = l & 15;
  const int kq = (l >> 4) * 8;
  floatx4 acc[4][4];
#pragma unroll
  for (int i = 0; i < 4; ++i)
#pragma unroll
    for (int j = 0; j < 4; ++j) { floatx4 z = {0.f, 0.f, 0.f, 0.f}; acc[i][j] = z; }

  for (int k0 = 0; k0 < 512; k0 += 32) {
    halfx8 af[4], bf[4];
#pragma unroll
    for (int i = 0; i < 4; ++i) {
      af[i] = *(const halfx8*)(hh + (size_t)(m0 + i * 16 + fr) * 512 + k0 + kq);
      bf[i] = *(const halfx8*)(Bp + (size_t)(n0 + i * 16 + fr) * 512 + k0 + kq);
    }
#pragma unroll
    for (int i = 0; i < 4; ++i)
#pragma unroll
      for (int j = 0; j < 4; ++j)
        acc[i][j] = __builtin_amdgcn_mfma_f32_16x16x32_f16(af[i], bf[j], acc[i][j], 0, 0, 0);
  }

#pragma unroll
  for (int j = 0; j < 4; ++j) {
    int n = n0 + j * 16 + (l & 15);
    float bv = isfc2 ? fc2b[n] : 0.0f;
#pragma unroll
    for (int i = 0; i < 4; ++i) {
      int mb = m0 + i * 16 + (l >> 4) * 4;
#pragma unroll
      for (int r = 0; r < 4; ++r) {
        float v = acc[i][j][r] + bv;
        if (isfc2) outp[(size_t)(mb + r) * 480000 + n] = v;
        else       ghq[(size_t)(mb + r) * 2048 + n] = v;
      }
    }
  }
}

// ---------------- scores: one wave per (b,s): tanh(q_b + kp_bs) . attv ----------------
__global__ __launch_bounds__(256) void k_scores(const half_t* __restrict__ kpfp,
                                                const float* __restrict__ ghq,
                                                const float* __restrict__ attv,
                                                float* __restrict__ scores) {
  int w = blockIdx.x * 4 + (threadIdx.x >> 6);   // 0..25087 == b*196+s
  int l = threadIdx.x & 63;
  int b = w / 196;
  halfx8 kv = *(const halfx8*)(kpfp + (size_t)w * 1024 + l * 8);
  const float* qr = ghq + (size_t)b * 2048 + 1536 + l * 8;
  float4 q0 = *(const float4*)qr;
  float4 q1 = *(const float4*)(qr + 4);
  float4 a0 = *(const float4*)(attv + l * 8);
  float4 a1 = *(const float4*)(attv + l * 8 + 4);
  float acc = a0.x * tanh_f(q0.x + (float)kv[0]);
  acc += a0.y * tanh_f(q0.y + (float)kv[1]);
  acc += a0.z * tanh_f(q0.z + (float)kv[2]);
  acc += a0.w * tanh_f(q0.w + (float)kv[3]);
  acc += a1.x * tanh_f(q1.x + (float)kv[4]);
  acc += a1.y * tanh_f(q1.y + (float)kv[5]);
  acc += a1.z * tanh_f(q1.z + (float)kv[6]);
  acc += a1.w * tanh_f(q1.w + (float)kv[7]);
#pragma unroll
  for (int off = 32; off > 0; off >>= 1) acc += __shfl_xor(acc, off, 64);
  if (l == 0) scores[w] = acc;
}

// ---------------- softmax + ctx = w @ featp (f16 out) ----------------
__global__ __launch_bounds__(256) void k_ctx(const float* __restrict__ scores,
                                             const half_t* __restrict__ kpfp,
                                             half_t* __restrict__ ctxo) {
  const int b = blockIdx.x, kt = blockIdx.y * 128, t = threadIdx.x;
  __shared__ float sw[196], red[256];
  float sc = (t < 196) ? scores[b * 196 + t] : -1e30f;
  red[t] = sc; __syncthreads();
  for (int o = 128; o > 0; o >>= 1) { if (t < o) red[t] = fmaxf(red[t], red[t + o]); __syncthreads(); }
  float mx = red[0]; __syncthreads();
  float e = (t < 196) ? __expf(sc - mx) : 0.f;
  red[t] = e; __syncthreads();
  for (int o = 128; o > 0; o >>= 1) { if (t < o) red[t] += red[t + o]; __syncthreads(); }
  float inv = 1.0f / red[0];
  if (t < 196) sw[t] = e * inv;
  __syncthreads();
  const int kk = t & 127, half = t >> 7, s0 = half * 98;
  const half_t* fp = kpfp + (size_t)(b * 196 + s0) * 1024 + 512 + kt + kk;
  float acc = 0.f;
#pragma unroll 7
  for (int i = 0; i < 98; ++i) acc += sw[s0 + i] * (float)fp[(size_t)i * 1024];
  red[t] = acc; __syncthreads();
  if (t < 128) ctxo[(size_t)b * 512 + kt + t] = (half_t)(red[t] + red[t + 128]);
}

// ---------------- GRU gates, elementwise ----------------
__global__ __launch_bounds__(256) void k_gates(const float* __restrict__ gix,
                                               const float* __restrict__ gic,
                                               const float* __restrict__ ghq,
                                               const float* __restrict__ bih,
                                               const float* __restrict__ bhh,
                                               float* __restrict__ hbuf,
                                               half_t* __restrict__ hh, int step) {
  int idx = blockIdx.x * 256 + threadIdx.x;  // 0..65535
  int b = idx >> 9, n = idx & 511;
  const float* gx = gix + (size_t)(b * 15 + step) * 1536;
  const float* gc = gic + (size_t)b * 1536;
  const float* gh = ghq + (size_t)b * 2048;
  float ir  = gx[n]        + gc[n]        + bih[n];
  float iz  = gx[n + 512]  + gc[n + 512]  + bih[n + 512];
  float in_ = gx[n + 1024] + gc[n + 1024] + bih[n + 1024];
  float hr  = gh[n]        + bhh[n];
  float hz  = gh[n + 512]  + bhh[n + 512];
  float hn  = gh[n + 1024] + bhh[n + 1024];
  float r = sigmoid_f(ir + hr);
  float z = sigmoid_f(iz + hz);
  float nn = tanh_f(in_ + r * hn);
  float hv = (1.0f - z) * nn + z * hbuf[idx];
  hbuf[idx] = hv;
  hh[idx] = (half_t)hv;
}

extern "C" void kernel_launch(void* const* d_in, const int* in_sizes, int n_in,
                              void* d_out, int out_size, void* d_ws, size_t ws_size,
                              hipStream_t stream) {
  (void)in_sizes; (void)n_in; (void)out_size; (void)ws_size;
  const float* features = (const float*)d_in[0];
  const int*   captions = (const int*)d_in[1];
  const float* emb      = (const float*)d_in[2];
  const float* fc1_w    = (const float*)d_in[3];
  const float* fc1_b    = (const float*)d_in[4];
  const float* att_wq   = (const float*)d_in[5];
  const float* att_wk   = (const float*)d_in[6];
  const float* att_v    = (const float*)d_in[7];
  const float* fc0_w    = (const float*)d_in[8];
  const float* fc0_b    = (const float*)d_in[9];
  const float* gru_wih  = (const float*)d_in[10];
  const float* gru_whh  = (const float*)d_in[11];
  const float* gru_bih  = (const float*)d_in[12];
  const float* gru_bhh  = (const float*)d_in[13];
  const float* fc2_w    = (const float*)d_in[14];
  const float* fc2_b    = (const float*)d_in[15];
  float* out = (float*)d_out;

  // workspace layout (~109 MB)
  char* p = (char*)d_ws;
  half_t* kpfp   = (half_t*)p; p += (size_t)25088 * 1024 * 2; // [:,0:512]=kp, [:,512:1024]=featp+fc0_b
  half_t* fc2w_h = (half_t*)p; p += (size_t)32000 * 512 * 2;
  float*  gix    = (float*)p;  p += (size_t)1920 * 1536 * 4;  // x-path GRU gates, all t
  half_t* wihx_h = (half_t*)p; p += (size_t)1536 * 512 * 2;
  half_t* wihc_h = (half_t*)p; p += (size_t)1536 * 512 * 2;
  half_t* bcat2  = (half_t*)p; p += (size_t)2048 * 512 * 2;   // rows 0:1536=whh, 1536:2048=wq
  half_t* wkfc0  = (half_t*)p; p += (size_t)1024 * 512 * 2;   // rows 0:512=att_wk, 512:1024=fc0_w
  half_t* fc1w_h = (half_t*)p; p += (size_t)512 * 512 * 2;
  half_t* embg_h = (half_t*)p; p += (size_t)1920 * 512 * 2;
  half_t* xproj_h= (half_t*)p; p += (size_t)1920 * 512 * 2;
  float*  biasc  = (float*)p;  p += (size_t)1024 * 4;
  float*  ghq    = (float*)p;  p += (size_t)128 * 2048 * 4;   // cols 0:1536=gh, 1536:2048=q
  float*  hbuf   = (float*)p;  p += (size_t)128 * 512 * 4;    // contiguous after ghq (zeroed together)
  float*  scores = (float*)p;  p += (size_t)128 * 196 * 4;
  float*  gic    = (float*)p;  p += (size_t)128 * 1536 * 4;
  half_t* ctxo   = (half_t*)p; p += (size_t)128 * 512 * 2;
  half_t* h_h    = (half_t*)p; p += (size_t)128 * 512 * 2;

  // ---- precompute ----
  k_cvt_f16<<<dim3(16000), 256, 0, stream>>>(fc2_w, fc2w_h, 32000 * 512);
  k_cvt_f16<<<dim3(256),   256, 0, stream>>>(fc1_w, fc1w_h, 512 * 512);
  k_cvt_f16<<<dim3(256),   256, 0, stream>>>(att_wk, wkfc0, 512 * 512);
  k_cvt_f16<<<dim3(256),   256, 0, stream>>>(fc0_w, wkfc0 + (size_t)512 * 512, 512 * 512);
  k_cvt_f16<<<dim3(768),   256, 0, stream>>>(gru_whh, bcat2, 1536 * 512);
  k_cvt_f16<<<dim3(256),   256, 0, stream>>>(att_wq, bcat2 + (size_t)1536 * 512, 512 * 512);
  k_wihsplit<<<dim3(1536), 256, 0, stream>>>(gru_wih, wihx_h, wihc_h);
  k_gather<<<dim3(1920), 256, 0, stream>>>(emb, captions, embg_h);
  k_biasc<<<dim3(4), 256, 0, stream>>>(fc0_b, biasc);
  // zero ghq (1 MB) + hbuf (256 KB): 81920 float4
  k_zero<<<dim3(320), 256, 0, stream>>>((float4*)ghq);
  // xproj = embg @ fc1_w^T + fc1_b  (1920 x 512, f16 out)
  k_gemm_bt<false, true><<<dim3(15, 4), 256, 0, stream>>>(embg_h, fc1w_h, fc1_b, xproj_h, 512, 512);
  // kpfp = features @ [wk|fc0]^T + [0|fc0_b]  (25088 x 1024, f16 out)
  k_gemm_bt<true, true><<<dim3(196, 8), 256, 0, stream>>>(features, wkfc0, biasc, kpfp, 512, 1024);
  // gix = xproj @ wihx^T  (1920 x 1536, f32 out)
  k_gemm_bt<false, false><<<dim3(15, 12), 256, 0, stream>>>(xproj_h, wihx_h, nullptr, gix, 512, 1536);

  // ---- decode loop ----
  for (int t = 0; t < 15; ++t) {
    k_scores<<<dim3(6272), 256, 0, stream>>>(kpfp, ghq, att_v, scores);
    k_ctx<<<dim3(128, 4), 256, 0, stream>>>(scores, kpfp, ctxo);
    // gic = ctxo @ wihc^T  (128 x 1536)
    k_gemm_bt<false, false><<<dim3(1, 12), 256, 0, stream>>>(ctxo, wihc_h, nullptr, gic, 512, 1536);
    k_gates<<<dim3(256), 256, 0, stream>>>(gix, gic, ghq, gru_bih, gru_bhh, hbuf, h_h, t);
    // out[:,t,:] = h @ fc2^T + fc2_b ; ghq = h @ [whh|wq]^T (for step t+1)
    k_fc2gru<<<dim3(266), 256, 0, stream>>>(h_h, fc2w_h, fc2_b, bcat2, out + (size_t)t * 32000, ghq);
  }
}